// Round 10
// baseline (353.313 us; speedup 1.0000x reference)
//
#include <hip/hip_runtime.h>

typedef __bf16 bf16_t;
typedef __bf16 bf16x8 __attribute__((ext_vector_type(8)));
typedef __bf16 bf16x4 __attribute__((ext_vector_type(4)));
typedef float  f32x4  __attribute__((ext_vector_type(4)));

// padded j-strides (elements): break the 1MiB L2-set alias on per-j planes
#define PHI_JS  (4096 * 128 + 64)
#define PSIU_JS (4032 * 128 + 64)

// ---------------------------------------------------------------------------
// ONE preprocessing launch, independent blocks (verbatim R8/R9):
//   [0,4096)      xW2 transpose  (fp32 [j][256][256] -> bf16 [j][256][256]^T)
//   [4096,8192)   uW2 transpose
//   [8192,10240)  xW3 transpose + x_scale fold
//   [10240,12288) uW3 transpose + u_scale fold
//   [12288,12416) prep_w1 (gamma fold, transpose, K-pad; beta fold into b1)
//   [12416,12512) bn_partial (per-feature sum/sumsq partials)
//   [12512,12576) zero d_out (y/ypred accumulated by scan via atomics)
__global__ __launch_bounds__(256) void prep_all_kernel(
    const float* __restrict__ xW1, const float* __restrict__ xb1,
    const float* __restrict__ xg,  const float* __restrict__ xbeta,
    const float* __restrict__ uW1, const float* __restrict__ ub1,
    const float* __restrict__ ug,  const float* __restrict__ ubeta,
    const float* __restrict__ xW2, const float* __restrict__ uW2,
    const float* __restrict__ xW3, const float* __restrict__ uW3,
    const float* __restrict__ x_scale, const float* __restrict__ u_scale,
    const float* __restrict__ xs, const float* __restrict__ us,
    bf16_t* __restrict__ xW1t, float* __restrict__ xb1p,
    bf16_t* __restrict__ uW1t, float* __restrict__ ub1p,
    bf16_t* __restrict__ xW2t, bf16_t* __restrict__ uW2t,
    bf16_t* __restrict__ xW3t, bf16_t* __restrict__ uW3t,
    float* __restrict__ part, float* __restrict__ zout)
{
    const int t = blockIdx.x, tid = threadIdx.x;
    __shared__ float tile[32][33];
    __shared__ float h1[256], h2[256];

    if (t < 12288) {
        // ---- weight transposes ----
        const float* in; bf16_t* outp; const float* scale = nullptr;
        int j, r0, c0, C;
        if (t < 8192) {
            C = 256;
            j = (t & 4095) >> 6;
            const int tl = t & 63; r0 = (tl >> 3) * 32; c0 = (tl & 7) * 32;
            if (t < 4096) { in = xW2; outp = xW2t; }
            else          { in = uW2; outp = uW2t; }
        } else {
            C = 128;
            const int l = t - 8192;
            j = (l & 2047) >> 5;
            const int tl = l & 31; r0 = (tl >> 2) * 32; c0 = (tl & 3) * 32;
            if (l < 2048) { in = xW3; outp = xW3t; scale = x_scale + j * 128; }
            else          { in = uW3; outp = uW3t; scale = u_scale + j * 128; }
        }
        const int R = 256;
        in   += (size_t)j * R * C;
        bf16_t* op = outp + (size_t)j * R * C;
        const int tx = tid & 31, ty = tid >> 5;
        #pragma unroll
        for (int i = 0; i < 4; i++)
            tile[ty + i * 8][tx] = in[(size_t)(r0 + ty + i * 8) * C + c0 + tx];
        __syncthreads();
        #pragma unroll
        for (int i = 0; i < 4; i++) {
            int c = c0 + ty + i * 8;
            float sc = scale ? scale[c] : 1.f;
            op[(size_t)c * R + r0 + tx] = (bf16_t)(tile[tx][ty + i * 8] * sc);
        }
    } else if (t < 12416) {
        // ---- prep_w1 ----
        const int bid = t - 12288, j = bid & 63, h = tid;
        const float *W1, *b1, *gamma, *beta; bf16_t* W1t; float* b1p; int D;
        if (bid < 64) { W1 = xW1; b1 = xb1; gamma = xg; beta = xbeta; W1t = xW1t; b1p = xb1p; D = 16; }
        else          { W1 = uW1; b1 = ub1; gamma = ug; beta = ubeta; W1t = uW1t; b1p = ub1p; D = 8; }
        float bacc = b1[j * 256 + h];
        bf16_t* orow = W1t + (size_t)(j * 256 + h) * 32;
        for (int d = 0; d < 32; d++) orow[d] = (bf16_t)0.f;
        for (int d = 0; d < D; d++) {
            float w = W1[((size_t)j * D + d) * 256 + h];
            orow[d] = (bf16_t)(gamma[j * D + d] * w);
            bacc += beta[j * D + d] * w;
        }
        b1p[j * 256 + h] = bacc;
    } else if (t < 12512) {
        // ---- bn_partial ----
        const int bid = t - 12416;
        const bool isx = bid < 64;
        const float* x = isx ? xs : us;
        const int D   = isx ? 16 : 8;
        const int lb  = isx ? bid : bid - 64;
        const int per = isx ? 1024 : 1008;
        const int start = lb * per;
        float a = 0.f, b = 0.f;
        for (int idx = start + tid; idx < start + per; idx += 256) {
            float v = x[idx];
            a += v; b += v * v;
        }
        float* s1 = h1; float* s2 = h2;
        s1[tid] = a; s2[tid] = b;
        __syncthreads();
        if (tid < D) {
            float sa = 0.f, sb = 0.f;
            for (int k = tid; k < 256; k += D) { sa += s1[k]; sb += s2[k]; }
            part[bid * 32 + tid]      = sa;
            part[bid * 32 + 16 + tid] = sb;
        }
    } else {
        // ---- zero y/ypred outputs (scan accumulates via atomicAdd) ----
        const int g = (t - 12512) * 256 + tid;      // 0..16383
        for (int i = g; i < 2 * 64 * 63 * 16; i += 64 * 256)
            zout[i] = 0.f;
    }
}

// ---------------------------------------------------------------------------
// Fused BN + 3-layer MLP — EXACT R0 structure (174-180 µs verified across
// R0/R2/R5/R6/R7/R8/R9). R1 (3 blocks/CU) hit the register wall (spill);
// R3/R4 (M-split) doubled per-wave weight vmem. 2 blocks/CU + zero weight
// duplication is the feasible optimum. Blocks bid>=4096 compute psi0.
__global__ __launch_bounds__(512, 4) void fused_mlp_kernel(
    const float* __restrict__ xs, const float* __restrict__ us,
    const float* __restrict__ part,
    const bf16_t* __restrict__ xW1t, const float* __restrict__ xb1p,
    const bf16_t* __restrict__ xW2t, const float* __restrict__ xb2,
    const bf16_t* __restrict__ xW3t,
    const bf16_t* __restrict__ uW1t, const float* __restrict__ ub1p,
    const bf16_t* __restrict__ uW2t, const float* __restrict__ ub2,
    const bf16_t* __restrict__ uW3t,
    const float* __restrict__ uW1r, const float* __restrict__ ub1r,
    const float* __restrict__ ubetar, const float* __restrict__ uW2r,
    const float* __restrict__ uW3r, const float* __restrict__ u_scaler,
    float* __restrict__ psi0_out,
    bf16_t* __restrict__ phi, bf16_t* __restrict__ psiu)
{
    const int bid  = blockIdx.x;
    const int tid  = threadIdx.x;

    __shared__ __align__(16) bf16_t hs[128 * 256];   // 64 KB, reused
    __shared__ float stats_s[32];                    // [mu(16), rstd(16)]

    if (bid >= 4096) {
        // ---------------- psi0 (512 threads, split-K) ----------------
        const int j = bid - 4096;
        float* fb  = (float*)hs;          // h1[256] | h2[256] | tmp[512]
        float* h1  = fb;
        float* h2  = fb + 256;
        float* tmp = fb + 512;
        const int h = tid & 255, half = tid >> 8;
        if (half == 0) {
            float bacc = ub1r[j * 256 + h];
            #pragma unroll
            for (int d = 0; d < 8; d++)
                bacc += ubetar[j * 8 + d] * uW1r[((size_t)j * 8 + d) * 256 + h];
            h1[h] = fmaxf(bacc, 0.01f * bacc);
        }
        __syncthreads();
        {
            float acc = (half == 0) ? ub2[j * 256 + h] : 0.f;
            const float* w2 = uW2r + (size_t)j * 65536 + (size_t)half * 128 * 256 + h;
            #pragma unroll 16
            for (int d = 0; d < 128; d++) acc += h1[half * 128 + d] * w2[(size_t)d * 256];
            tmp[tid] = acc;
        }
        __syncthreads();
        if (half == 0) {
            float v = tmp[h] + tmp[h + 256];
            h2[h] = fmaxf(v, 0.01f * v);
        }
        __syncthreads();
        {
            const int h3 = tid & 127, qd = tid >> 7;   // 0..3
            float acc = 0.f;
            const float* w3 = uW3r + (size_t)j * 32768 + (size_t)qd * 64 * 128 + h3;
            #pragma unroll 16
            for (int d = 0; d < 64; d++) acc += h2[qd * 64 + d] * w3[(size_t)d * 128];
            tmp[tid] = acc;
        }
        __syncthreads();
        if (tid < 128)
            psi0_out[j * 128 + tid] =
                (tmp[tid] + tmp[tid + 128] + tmp[tid + 256] + tmp[tid + 384])
                * u_scaler[j * 128 + tid];
        return;
    }

    const int xcd  = bid & 7;
    const int slot = bid >> 3;          // 0..511
    const int band = slot >> 6;         // 0..7
    const int t64  = slot & 63;
    const int j    = xcd * 8 + band;
    const bool is_x = t64 < 32;
    const int tile  = is_x ? t64 : (t64 - 32);

    const float*  In  = is_x ? xs   : us;
    const int     D   = is_x ? 16   : 8;
    const bf16_t* W1t = is_x ? xW1t : uW1t;
    const float*  b1p = is_x ? xb1p : ub1p;
    const bf16_t* W2t = is_x ? xW2t : uW2t;
    const float*  b2  = is_x ? xb2  : ub2;
    const bf16_t* W3t = is_x ? xW3t : uW3t;
    bf16_t* outp      = is_x ? phi  : psiu;
    const int M       = is_x ? 4096 : 4032;
    const size_t JS   = is_x ? (size_t)PHI_JS : (size_t)PSIU_JS;

    const int row0 = tile * 128;
    const int wave = tid >> 6;          // 0..7
    const int lane = tid & 63;
    const int quad = lane >> 4;
    const int l16  = lane & 15;
    const int lo2  = l16 & 3, hi2 = l16 >> 2;

    // ---- inline BN final ----
    if (tid < 16) {
        if (is_x) {
            float sa = 0.f, sb = 0.f;
            #pragma unroll 8
            for (int b = 0; b < 64; b++) { sa += part[b * 32 + tid]; sb += part[b * 32 + 16 + tid]; }
            float mu = sa / 4096.f, var = sb / 4096.f - mu * mu;
            stats_s[tid] = mu; stats_s[16 + tid] = rsqrtf(var + 1e-5f);
        } else if (tid < 8) {
            float sa = 0.f, sb = 0.f;
            #pragma unroll 8
            for (int b = 64; b < 96; b++) { sa += part[b * 32 + tid]; sb += part[b * 32 + 16 + tid]; }
            float mu = sa / 4032.f, var = sb / 4032.f - mu * mu;
            stats_s[tid] = mu; stats_s[16 + tid] = rsqrtf(var + 1e-5f);
        }
    }
    __syncthreads();

    const f32x4 vzero = {0.f, 0.f, 0.f, 0.f};

    // per-thread swizzle constants (bytes)
    char* const hsB = (char*)hs;
    const char* const abase = hsB + l16 * 512 + ((quad ^ lo2) << 4);   // A-frag reads
    const int  wlow0 = (quad >> 1) ^ lo2;
    char* const wbase = hsB + l16 * 512 + ((wave ^ hi2) << 6) + ((quad & 1) << 3);

    // ---------------- layer 1 (K=32, BN folded in) ----------------
    {
        bf16x8 wfr[2];
        #pragma unroll
        for (int nbi = 0; nbi < 2; nbi++)
            wfr[nbi] = *reinterpret_cast<const bf16x8*>(
                W1t + (size_t)(j * 256 + wave * 32 + nbi * 16 + l16) * 32 + quad * 8);

        f32x4 acc[8][2];
        #pragma unroll
        for (int a = 0; a < 8; a++) { acc[a][0] = vzero; acc[a][1] = vzero; }

        const int c0 = quad * 8;
        #pragma unroll
        for (int mb = 0; mb < 8; mb++) {
            bf16x8 a;
            if (c0 < D) {
                int row = row0 + mb * 16 + l16;
                if (row > M - 1) row = M - 1;
                const float* xp = In + (size_t)row * D + c0;
                f32x4 v0 = *reinterpret_cast<const f32x4*>(xp);
                f32x4 v1 = *reinterpret_cast<const f32x4*>(xp + 4);
                #pragma unroll
                for (int e = 0; e < 4; e++) a[e]     = (bf16_t)((v0[e] - stats_s[c0 + e])     * stats_s[16 + c0 + e]);
                #pragma unroll
                for (int e = 0; e < 4; e++) a[4 + e] = (bf16_t)((v1[e] - stats_s[c0 + 4 + e]) * stats_s[16 + c0 + 4 + e]);
            } else {
                #pragma unroll
                for (int e = 0; e < 8; e++) a[e] = (bf16_t)0.f;
            }
            #pragma unroll
            for (int nbi = 0; nbi < 2; nbi++)
                acc[mb][nbi] = __builtin_amdgcn_mfma_f32_16x16x32_bf16(
                    wfr[nbi], a, acc[mb][nbi], 0, 0, 0);
        }

        #pragma unroll
        for (int nbi = 0; nbi < 2; nbi++) {
            const f32x4 bias = *reinterpret_cast<const f32x4*>(
                b1p + j * 256 + wave * 32 + nbi * 16 + quad * 4);
            char* wp = wbase + ((wlow0 ^ (nbi << 1)) << 4);
            #pragma unroll
            for (int mb = 0; mb < 8; mb++) {
                bf16x4 pk;
                #pragma unroll
                for (int r = 0; r < 4; r++) {
                    float v = acc[mb][nbi][r] + bias[r];
                    v = fmaxf(v, 0.01f * v);
                    pk[r] = (bf16_t)v;
                }
                *reinterpret_cast<bf16x4*>(wp + mb * 8192) = pk;
            }
        }
    }
    __syncthreads();

    // ---------------- layer 2 (256x256), depth-3 weight ring ----------------
    {
        f32x4 acc[8][2];
        #pragma unroll
        for (int a = 0; a < 8; a++) { acc[a][0] = vzero; acc[a][1] = vzero; }

        const bf16_t* w2base = W2t + ((size_t)j * 256 + wave * 32 + l16) * 256 + quad * 8;

        bf16x8 wr[3][2];
        #pragma unroll
        for (int d = 0; d < 3; d++)
            #pragma unroll
            for (int nbi = 0; nbi < 2; nbi++)
                wr[d][nbi] = *reinterpret_cast<const bf16x8*>(w2base + nbi * 4096 + d * 32);

        #pragma unroll
        for (int kk = 0; kk < 8; kk++) {
            const int c = kk % 3;
            const char* ap = abase + ((kk ^ hi2) << 6);
            bf16x8 av0[4];
            #pragma unroll
            for (int mb = 0; mb < 4; mb++)
                av0[mb] = *reinterpret_cast<const bf16x8*>(ap + mb * 8192);
            #pragma unroll
            for (int nbi = 0; nbi < 2; nbi++)
                #pragma unroll
                for (int mb = 0; mb < 4; mb++)
                    acc[mb][nbi] = __builtin_amdgcn_mfma_f32_16x16x32_bf16(
                        wr[c][nbi], av0[mb], acc[mb][nbi], 0, 0, 0);
            bf16x8 av1[4];
            #pragma unroll
            for (int mb = 0; mb < 4; mb++)
                av1[mb] = *reinterpret_cast<const bf16x8*>(ap + (mb + 4) * 8192);
            #pragma unroll
            for (int nbi = 0; nbi < 2; nbi++)
                #pragma unroll
                for (int mb = 4; mb < 8; mb++)
                    acc[mb][nbi] = __builtin_amdgcn_mfma_f32_16x16x32_bf16(
                        wr[c][nbi], av1[mb - 4], acc[mb][nbi], 0, 0, 0);
            if (kk < 5) {
                #pragma unroll
                for (int nbi = 0; nbi < 2; nbi++)
                    wr[c][nbi] = *reinterpret_cast<const bf16x8*>(
                        w2base + nbi * 4096 + (kk + 3) * 32);
            }
        }
        __syncthreads();
        #pragma unroll
        for (int nbi = 0; nbi < 2; nbi++) {
            const f32x4 bias = *reinterpret_cast<const f32x4*>(
                b2 + j * 256 + wave * 32 + nbi * 16 + quad * 4);
            char* wp = wbase + ((wlow0 ^ (nbi << 1)) << 4);
            #pragma unroll
            for (int mb = 0; mb < 8; mb++) {
                bf16x4 pk;
                #pragma unroll
                for (int r = 0; r < 4; r++) {
                    float v = acc[mb][nbi][r] + bias[r];
                    v = fmaxf(v, 0.01f * v);
                    pk[r] = (bf16_t)v;
                }
                *reinterpret_cast<bf16x4*>(wp + mb * 8192) = pk;
            }
        }
    }
    __syncthreads();

    // ---------------- layer 3 (256x128), depth-3 weight ring ----------------
    {
        f32x4 acc[8];
        #pragma unroll
        for (int a = 0; a < 8; a++) acc[a] = vzero;

        const bf16_t* w3base = W3t + ((size_t)j * 128 + wave * 16 + l16) * 256 + quad * 8;

        bf16x8 wr[3];
        #pragma unroll
        for (int d = 0; d < 3; d++)
            wr[d] = *reinterpret_cast<const bf16x8*>(w3base + d * 32);

        #pragma unroll
        for (int kk = 0; kk < 8; kk++) {
            const int c = kk % 3;
            const char* ap = abase + ((kk ^ hi2) << 6);
            bf16x8 av0[4];
            #pragma unroll
            for (int mb = 0; mb < 4; mb++)
                av0[mb] = *reinterpret_cast<const bf16x8*>(ap + mb * 8192);
            #pragma unroll
            for (int mb = 0; mb < 4; mb++)
                acc[mb] = __builtin_amdgcn_mfma_f32_16x16x32_bf16(
                    wr[c], av0[mb], acc[mb], 0, 0, 0);
            bf16x8 av1[4];
            #pragma unroll
            for (int mb = 0; mb < 4; mb++)
                av1[mb] = *reinterpret_cast<const bf16x8*>(ap + (mb + 4) * 8192);
            #pragma unroll
            for (int mb = 4; mb < 8; mb++)
                acc[mb] = __builtin_amdgcn_mfma_f32_16x16x32_bf16(
                    wr[c], av1[mb - 4], acc[mb], 0, 0, 0);
            if (kk < 5)
                wr[c] = *reinterpret_cast<const bf16x8*>(w3base + (kk + 3) * 32);
        }
        __syncthreads();   // hs reusable as [128][128]
        {
            const int sp3 = (wave * 2 + (quad >> 1)) ^ l16;
            char* w3p = hsB + l16 * 256 + sp3 * 16 + ((quad & 1) << 3);
            #pragma unroll
            for (int mb = 0; mb < 8; mb++) {
                bf16x4 pk;
                #pragma unroll
                for (int r = 0; r < 4; r++) pk[r] = (bf16_t)acc[mb][r];
                *reinterpret_cast<bf16x4*>(w3p + mb * 4096) = pk;
            }
        }
    }
    __syncthreads();
    #pragma unroll
    for (int p = 0; p < 4; p++) {
        const int rr = p * 32 + (tid >> 4);
        const int s  = tid & 15;
        if (row0 + rr < M) {
            bf16x8 v = *reinterpret_cast<const bf16x8*>(hs + rr * 128 + (s ^ (rr & 15)) * 8);
            *reinterpret_cast<bf16x8*>(outp + (size_t)j * JS + (size_t)(row0 + rr) * 128 + s * 8) = v;
        }
    }
}

// ---------------------------------------------------------------------------
// Koopman scan v4 — barrier-free iterations via in-wave net-sum.
// Grid 512 = 64 b x 8 jg, 512 threads. Lane = (net_sub = lane>>3, p_lo =
// lane&7); pair = wave*8 + p_lo; net j0 = jg*8 + net_sub. Each thread runs
// one (net, pair) recurrence; the 8-net sum is 3 shfl_xor steps (masks
// 8/16/32) — NO __syncthreads in the iteration chain. Each wave owns a
// disjoint 16-col slice of SPb/SYb, so slot writes need no sync; the only
// barriers are 2 per 8-t decode flush (16 total vs R9's 32+8). Loads are
// batched 8-t-deep (16 independent 4B loads in flight per chunk). Decode
// flush (CsT matvec + atomicAdd into prep-zeroed out) verbatim R8/R9.
// Net-sum order: tree (shfl) vs linear — fp-rounding change only.
__global__ __launch_bounds__(512) void scan_kernel(
    const bf16_t* __restrict__ phi, const bf16_t* __restrict__ psiu,
    const float* __restrict__ psi0, const float* __restrict__ reL,
    const float* __restrict__ imL, const float* __restrict__ C_W,
    float* __restrict__ y, float* __restrict__ ypred) {
    const int b = blockIdx.x >> 3, jg = blockIdx.x & 7;
    const int tid = threadIdx.x;
    const int wave = tid >> 6, lane = tid & 63;
    const int net_sub = lane >> 3;       // 0..7 : net within jg-group
    const int p_lo = lane & 7;
    const int pair = wave * 8 + p_lo;    // 0..63 : complex pair index
    __shared__ float SPb[8][132];
    __shared__ float SYb[8][132];
    __shared__ float CsT[2048];          // CsT[i*16+o] = C_W[o*128+i]
    #pragma unroll
    for (int i = 0; i < 4; i++) {
        const int idx = tid + i * 512;
        CsT[(idx & 127) * 16 + (idx >> 7)] = C_W[idx];
    }
    __syncthreads();

    const int j0 = jg * 8 + net_sub;
    float sx, sy, p0x, p0y, lre, lim;
    {
        unsigned v = *reinterpret_cast<const unsigned*>(
            phi + (size_t)j0 * PHI_JS + (size_t)(b * 64) * 128 + pair * 2);
        sx = __uint_as_float(v << 16); sy = __uint_as_float(v & 0xFFFF0000u);
        float2 p0 = *reinterpret_cast<const float2*>(psi0 + j0 * 128 + pair * 2);
        p0x = p0.x; p0y = p0.y;
        lre = reL[j0]; lim = imL[j0];
    }
    const bf16_t* up = psiu + (size_t)j0 * PSIU_JS + (size_t)(b * 63) * 128 + pair * 2;
    const bf16_t* pp = phi  + (size_t)j0 * PHI_JS  + (size_t)(b * 64 + 1) * 128 + pair * 2;

    const int ds  = (tid >> 7) & 1;      // decode: stream (tid<256 active)
    const int dr  = tid & 127;
    const int dtt = dr >> 4, doo = dr & 15;
    const int pcol = pair * 2;

    unsigned ub[2][8], pb[2][8];
    #pragma unroll
    for (int i = 0; i < 8; i++) {
        ub[0][i] = *reinterpret_cast<const unsigned*>(up + i * 128);
        pb[0][i] = *reinterpret_cast<const unsigned*>(pp + i * 128);
    }

    #pragma unroll
    for (int c = 0; c < 8; c++) {
        const int cb = c & 1;
        if (c < 7) {
            #pragma unroll
            for (int i = 0; i < 8; i++) {
                const int tn = (c + 1) * 8 + i;
                if (tn < 63) {
                    ub[cb ^ 1][i] = *reinterpret_cast<const unsigned*>(up + tn * 128);
                    pb[cb ^ 1][i] = *reinterpret_cast<const unsigned*>(pp + tn * 128);
                }
            }
        }
        const int n = (c == 7) ? 7 : 8;
        #pragma unroll
        for (int i = 0; i < 8; i++) {
            if (i < n) {
                const unsigned u = ub[cb][i];
                float px = sx + (__uint_as_float(u << 16) - p0x);
                float py = sy + (__uint_as_float(u & 0xFFFF0000u) - p0y);
                sx = px * lre - py * lim;
                sy = px * lim + py * lre;
                const unsigned ph = pb[cb][i];
                float rx = sx, ry = sy;
                float yx = __uint_as_float(ph << 16);
                float yy = __uint_as_float(ph & 0xFFFF0000u);
                rx += __shfl_xor(rx, 8);  ry += __shfl_xor(ry, 8);
                yx += __shfl_xor(yx, 8);  yy += __shfl_xor(yy, 8);
                rx += __shfl_xor(rx, 16); ry += __shfl_xor(ry, 16);
                yx += __shfl_xor(yx, 16); yy += __shfl_xor(yy, 16);
                rx += __shfl_xor(rx, 32); ry += __shfl_xor(ry, 32);
                yx += __shfl_xor(yx, 32); yy += __shfl_xor(yy, 32);
                if (net_sub < 2) {
                    SPb[i][pcol + net_sub] = net_sub ? ry : rx;
                    SYb[i][pcol + net_sub] = net_sub ? yy : yx;
                }
            }
        }
        // ---- bulk decode flush for this chunk ----
        __syncthreads();
        if (tid < 256 && dtt < n) {
            const float* S = ds ? SYb[dtt] : SPb[dtt];
            float acc = 0.f;
            #pragma unroll
            for (int i = 0; i < 128; i++) acc += S[i] * CsT[i * 16 + doo];
            float* dst = ds ? (y     + (b * 63 + c * 8 + dtt) * 16 + doo)
                            : (ypred + (b * 63 + c * 8 + dtt) * 16 + doo);
            atomicAdd(dst, acc);
        }
        __syncthreads();
    }
}

// ---------------------------------------------------------------------------
extern "C" void kernel_launch(void* const* d_in, const int* in_sizes, int n_in,
                              void* d_out, int out_size, void* d_ws, size_t ws_size,
                              hipStream_t stream) {
    const float* xs      = (const float*)d_in[0];
    const float* us      = (const float*)d_in[1];
    const float* x_gamma = (const float*)d_in[2];
    const float* x_beta  = (const float*)d_in[3];
    const float* xW1     = (const float*)d_in[4];
    const float* xb1     = (const float*)d_in[5];
    const float* xW2     = (const float*)d_in[6];
    const float* xb2     = (const float*)d_in[7];
    const float* xW3     = (const float*)d_in[8];
    const float* x_scale = (const float*)d_in[9];
    const float* u_gamma = (const float*)d_in[10];
    const float* u_beta  = (const float*)d_in[11];
    const float* uW1     = (const float*)d_in[12];
    const float* ub1     = (const float*)d_in[13];
    const float* uW2     = (const float*)d_in[14];
    const float* ub2     = (const float*)d_in[15];
    const float* uW3     = (const float*)d_in[16];
    const float* u_scale = (const float*)d_in[17];
    const float* reL     = (const float*)d_in[18];
    const float* imL     = (const float*)d_in[19];
    const float* C_W     = (const float*)d_in[20];

    char* ws = (char*)d_ws;
    size_t off = 0;
    auto alloc = [&](size_t bytes) -> char* {
        char* p = ws + off;
        off += (bytes + 255) & ~(size_t)255;
        return p;
    };
    float*  part = (float*)alloc(96 * 32 * 4);
    bf16_t* xW1t = (bf16_t*)alloc((size_t)64 * 256 * 32 * 2);
    float*  xb1p = (float*) alloc((size_t)64 * 256 * 4);
    bf16_t* xW2t = (bf16_t*)alloc((size_t)64 * 256 * 256 * 2);
    bf16_t* xW3t = (bf16_t*)alloc((size_t)64 * 128 * 256 * 2);
    bf16_t* uW1t = (bf16_t*)alloc((size_t)64 * 256 * 32 * 2);
    float*  ub1p = (float*) alloc((size_t)64 * 256 * 4);
    bf16_t* uW2t = (bf16_t*)alloc((size_t)64 * 256 * 256 * 2);
    bf16_t* uW3t = (bf16_t*)alloc((size_t)64 * 128 * 256 * 2);
    float*  psi0 = (float*) alloc((size_t)64 * 128 * 4);
    bf16_t* phi  = (bf16_t*)alloc((size_t)64 * PHI_JS  * 2);   // [j][4096][128] + pad
    bf16_t* psiu = (bf16_t*)alloc((size_t)64 * PSIU_JS * 2);   // [j][4032][128] + pad

    float* y_out     = (float*)d_out;
    float* ypred_out = y_out + 64 * 63 * 16;

    prep_all_kernel<<<12576, 256, 0, stream>>>(
        xW1, xb1, x_gamma, x_beta, uW1, ub1, u_gamma, u_beta,
        xW2, uW2, xW3, uW3, x_scale, u_scale, xs, us,
        xW1t, xb1p, uW1t, ub1p, xW2t, uW2t, xW3t, uW3t, part, y_out);
    fused_mlp_kernel<<<4160, 512, 0, stream>>>(
        xs, us, part,
        xW1t, xb1p, xW2t, xb2, xW3t, uW1t, ub1p, uW2t, ub2, uW3t,
        uW1, ub1, u_beta, uW2, uW3, u_scale, psi0,
        phi, psiu);
    scan_kernel<<<512, 512, 0, stream>>>(
        phi, psiu, psi0, reL, imL, C_W, y_out, ypred_out);
}

// Round 11
// 326.110 us; speedup vs baseline: 1.0834x; 1.0834x over previous
//
#include <hip/hip_runtime.h>

typedef __bf16 bf16_t;
typedef __bf16 bf16x8 __attribute__((ext_vector_type(8)));
typedef __bf16 bf16x4 __attribute__((ext_vector_type(4)));
typedef __bf16 bf16x2 __attribute__((ext_vector_type(2)));
typedef float  f32x4  __attribute__((ext_vector_type(4)));

// padded j-strides (elements): break the 1MiB L2-set alias on per-j planes
#define PHI_JS  (4096 * 128 + 64)
#define PSIU_JS (4032 * 128 + 64)

// ---------------------------------------------------------------------------
// ONE preprocessing launch, independent blocks.
// R11: transposes reworked to 64x64 tiles (was 32x32): 3072 blocks (was
// 12288), 16 in-flight loads/thread (was 4), bf16x2 stores (was scalar 2B).
// Mechanism: prep's BW floor is ~17us but 4 loads/thread + 2B stores left it
// issue/latency-bound; bigger tiles amortize.
//   [0,1024)     xW2 transpose   [1024,2048)  uW2 transpose
//   [2048,2560)  xW3 transpose   [2560,3072)  uW3 transpose (+scale fold)
//   [3072,3200)  prep_w1         [3200,3296)  bn_partial
//   [3296,3360)  zero d_out
__global__ __launch_bounds__(256) void prep_all_kernel(
    const float* __restrict__ xW1, const float* __restrict__ xb1,
    const float* __restrict__ xg,  const float* __restrict__ xbeta,
    const float* __restrict__ uW1, const float* __restrict__ ub1,
    const float* __restrict__ ug,  const float* __restrict__ ubeta,
    const float* __restrict__ xW2, const float* __restrict__ uW2,
    const float* __restrict__ xW3, const float* __restrict__ uW3,
    const float* __restrict__ x_scale, const float* __restrict__ u_scale,
    const float* __restrict__ xs, const float* __restrict__ us,
    bf16_t* __restrict__ xW1t, float* __restrict__ xb1p,
    bf16_t* __restrict__ uW1t, float* __restrict__ ub1p,
    bf16_t* __restrict__ xW2t, bf16_t* __restrict__ uW2t,
    bf16_t* __restrict__ xW3t, bf16_t* __restrict__ uW3t,
    float* __restrict__ part, float* __restrict__ zout)
{
    const int t = blockIdx.x, tid = threadIdx.x;
    __shared__ float tile64[64][65];     // 16.6 KB
    __shared__ float h1[256], h2[256];

    if (t < 3072) {
        // ---- weight transposes, 64x64 tiles ----
        const float* in; bf16_t* outp; const float* scale = nullptr;
        int j, r0, c0, C;
        if (t < 2048) {
            C = 256;
            j = (t & 1023) >> 4;
            const int tl = t & 15; r0 = (tl >> 2) * 64; c0 = (tl & 3) * 64;
            if (t < 1024) { in = xW2; outp = xW2t; }
            else          { in = uW2; outp = uW2t; }
        } else {
            C = 128;
            const int l = t - 2048;
            j = (l & 511) >> 3;
            const int tl = l & 7; r0 = (tl >> 1) * 64; c0 = (tl & 1) * 64;
            if (l < 512) { in = xW3; outp = xW3t; scale = x_scale + j * 128; }
            else         { in = uW3; outp = uW3t; scale = u_scale + j * 128; }
        }
        const int R = 256;
        in   += (size_t)j * R * C;
        bf16_t* op = outp + (size_t)j * R * C;
        const int tx = tid & 63, ty = tid >> 6;      // load: 64 lanes/row, 4 rows/pass
        #pragma unroll
        for (int i = 0; i < 16; i++)
            tile64[ty + i * 4][tx] = in[(size_t)(r0 + ty + i * 4) * C + c0 + tx];
        __syncthreads();
        const int rx = tid & 31, cy = tid >> 5;      // store: 32 lanes x bf16x2
        #pragma unroll
        for (int i = 0; i < 8; i++) {
            const int c = c0 + cy + i * 8;
            const float sc = scale ? scale[c] : 1.f;
            bf16x2 pk;
            pk[0] = (bf16_t)(tile64[rx * 2][c - c0] * sc);
            pk[1] = (bf16_t)(tile64[rx * 2 + 1][c - c0] * sc);
            *reinterpret_cast<bf16x2*>(op + (size_t)c * R + r0 + rx * 2) = pk;
        }
    } else if (t < 3200) {
        // ---- prep_w1 ----
        const int bid = t - 3072, j = bid & 63, h = tid;
        const float *W1, *b1, *gamma, *beta; bf16_t* W1t; float* b1p; int D;
        if (bid < 64) { W1 = xW1; b1 = xb1; gamma = xg; beta = xbeta; W1t = xW1t; b1p = xb1p; D = 16; }
        else          { W1 = uW1; b1 = ub1; gamma = ug; beta = ubeta; W1t = uW1t; b1p = ub1p; D = 8; }
        float bacc = b1[j * 256 + h];
        bf16_t* orow = W1t + (size_t)(j * 256 + h) * 32;
        for (int d = 0; d < 32; d++) orow[d] = (bf16_t)0.f;
        for (int d = 0; d < D; d++) {
            float w = W1[((size_t)j * D + d) * 256 + h];
            orow[d] = (bf16_t)(gamma[j * D + d] * w);
            bacc += beta[j * D + d] * w;
        }
        b1p[j * 256 + h] = bacc;
    } else if (t < 3296) {
        // ---- bn_partial ----
        const int bid = t - 3200;
        const bool isx = bid < 64;
        const float* x = isx ? xs : us;
        const int D   = isx ? 16 : 8;
        const int lb  = isx ? bid : bid - 64;
        const int per = isx ? 1024 : 1008;
        const int start = lb * per;
        float a = 0.f, b = 0.f;
        for (int idx = start + tid; idx < start + per; idx += 256) {
            float v = x[idx];
            a += v; b += v * v;
        }
        float* s1 = h1; float* s2 = h2;
        s1[tid] = a; s2[tid] = b;
        __syncthreads();
        if (tid < D) {
            float sa = 0.f, sb = 0.f;
            for (int k = tid; k < 256; k += D) { sa += s1[k]; sb += s2[k]; }
            part[bid * 32 + tid]      = sa;
            part[bid * 32 + 16 + tid] = sb;
        }
    } else {
        // ---- zero y/ypred outputs (scan accumulates via atomicAdd) ----
        const int g = (t - 3296) * 256 + tid;       // 0..16383
        for (int i = g; i < 2 * 64 * 63 * 16; i += 64 * 256)
            zout[i] = 0.f;
    }
}

// ---------------------------------------------------------------------------
// Fused BN + 3-layer MLP — EXACT R0 structure (174-180 µs verified across
// R0/R2/R5/R6/R7/R8/R9/R10). R1 (3 blocks/CU) hit the register wall (spill);
// R3/R4 (M-split) doubled per-wave weight vmem. 2 blocks/CU + zero weight
// duplication is the feasible optimum. Blocks bid>=4096 compute psi0.
__global__ __launch_bounds__(512, 4) void fused_mlp_kernel(
    const float* __restrict__ xs, const float* __restrict__ us,
    const float* __restrict__ part,
    const bf16_t* __restrict__ xW1t, const float* __restrict__ xb1p,
    const bf16_t* __restrict__ xW2t, const float* __restrict__ xb2,
    const bf16_t* __restrict__ xW3t,
    const bf16_t* __restrict__ uW1t, const float* __restrict__ ub1p,
    const bf16_t* __restrict__ uW2t, const float* __restrict__ ub2,
    const bf16_t* __restrict__ uW3t,
    const float* __restrict__ uW1r, const float* __restrict__ ub1r,
    const float* __restrict__ ubetar, const float* __restrict__ uW2r,
    const float* __restrict__ uW3r, const float* __restrict__ u_scaler,
    float* __restrict__ psi0_out,
    bf16_t* __restrict__ phi, bf16_t* __restrict__ psiu)
{
    const int bid  = blockIdx.x;
    const int tid  = threadIdx.x;

    __shared__ __align__(16) bf16_t hs[128 * 256];   // 64 KB, reused
    __shared__ float stats_s[32];                    // [mu(16), rstd(16)]

    if (bid >= 4096) {
        // ---------------- psi0 (512 threads, split-K) ----------------
        const int j = bid - 4096;
        float* fb  = (float*)hs;          // h1[256] | h2[256] | tmp[512]
        float* h1  = fb;
        float* h2  = fb + 256;
        float* tmp = fb + 512;
        const int h = tid & 255, half = tid >> 8;
        if (half == 0) {
            float bacc = ub1r[j * 256 + h];
            #pragma unroll
            for (int d = 0; d < 8; d++)
                bacc += ubetar[j * 8 + d] * uW1r[((size_t)j * 8 + d) * 256 + h];
            h1[h] = fmaxf(bacc, 0.01f * bacc);
        }
        __syncthreads();
        {
            float acc = (half == 0) ? ub2[j * 256 + h] : 0.f;
            const float* w2 = uW2r + (size_t)j * 65536 + (size_t)half * 128 * 256 + h;
            #pragma unroll 16
            for (int d = 0; d < 128; d++) acc += h1[half * 128 + d] * w2[(size_t)d * 256];
            tmp[tid] = acc;
        }
        __syncthreads();
        if (half == 0) {
            float v = tmp[h] + tmp[h + 256];
            h2[h] = fmaxf(v, 0.01f * v);
        }
        __syncthreads();
        {
            const int h3 = tid & 127, qd = tid >> 7;   // 0..3
            float acc = 0.f;
            const float* w3 = uW3r + (size_t)j * 32768 + (size_t)qd * 64 * 128 + h3;
            #pragma unroll 16
            for (int d = 0; d < 64; d++) acc += h2[qd * 64 + d] * w3[(size_t)d * 128];
            tmp[tid] = acc;
        }
        __syncthreads();
        if (tid < 128)
            psi0_out[j * 128 + tid] =
                (tmp[tid] + tmp[tid + 128] + tmp[tid + 256] + tmp[tid + 384])
                * u_scaler[j * 128 + tid];
        return;
    }

    const int xcd  = bid & 7;
    const int slot = bid >> 3;          // 0..511
    const int band = slot >> 6;         // 0..7
    const int t64  = slot & 63;
    const int j    = xcd * 8 + band;
    const bool is_x = t64 < 32;
    const int tile  = is_x ? t64 : (t64 - 32);

    const float*  In  = is_x ? xs   : us;
    const int     D   = is_x ? 16   : 8;
    const bf16_t* W1t = is_x ? xW1t : uW1t;
    const float*  b1p = is_x ? xb1p : ub1p;
    const bf16_t* W2t = is_x ? xW2t : uW2t;
    const float*  b2  = is_x ? xb2  : ub2;
    const bf16_t* W3t = is_x ? xW3t : uW3t;
    bf16_t* outp      = is_x ? phi  : psiu;
    const int M       = is_x ? 4096 : 4032;
    const size_t JS   = is_x ? (size_t)PHI_JS : (size_t)PSIU_JS;

    const int row0 = tile * 128;
    const int wave = tid >> 6;          // 0..7
    const int lane = tid & 63;
    const int quad = lane >> 4;
    const int l16  = lane & 15;
    const int lo2  = l16 & 3, hi2 = l16 >> 2;

    // ---- inline BN final ----
    if (tid < 16) {
        if (is_x) {
            float sa = 0.f, sb = 0.f;
            #pragma unroll 8
            for (int b = 0; b < 64; b++) { sa += part[b * 32 + tid]; sb += part[b * 32 + 16 + tid]; }
            float mu = sa / 4096.f, var = sb / 4096.f - mu * mu;
            stats_s[tid] = mu; stats_s[16 + tid] = rsqrtf(var + 1e-5f);
        } else if (tid < 8) {
            float sa = 0.f, sb = 0.f;
            #pragma unroll 8
            for (int b = 64; b < 96; b++) { sa += part[b * 32 + tid]; sb += part[b * 32 + 16 + tid]; }
            float mu = sa / 4032.f, var = sb / 4032.f - mu * mu;
            stats_s[tid] = mu; stats_s[16 + tid] = rsqrtf(var + 1e-5f);
        }
    }
    __syncthreads();

    const f32x4 vzero = {0.f, 0.f, 0.f, 0.f};

    // per-thread swizzle constants (bytes)
    char* const hsB = (char*)hs;
    const char* const abase = hsB + l16 * 512 + ((quad ^ lo2) << 4);   // A-frag reads
    const int  wlow0 = (quad >> 1) ^ lo2;
    char* const wbase = hsB + l16 * 512 + ((wave ^ hi2) << 6) + ((quad & 1) << 3);

    // ---------------- layer 1 (K=32, BN folded in) ----------------
    {
        bf16x8 wfr[2];
        #pragma unroll
        for (int nbi = 0; nbi < 2; nbi++)
            wfr[nbi] = *reinterpret_cast<const bf16x8*>(
                W1t + (size_t)(j * 256 + wave * 32 + nbi * 16 + l16) * 32 + quad * 8);

        f32x4 acc[8][2];
        #pragma unroll
        for (int a = 0; a < 8; a++) { acc[a][0] = vzero; acc[a][1] = vzero; }

        const int c0 = quad * 8;
        #pragma unroll
        for (int mb = 0; mb < 8; mb++) {
            bf16x8 a;
            if (c0 < D) {
                int row = row0 + mb * 16 + l16;
                if (row > M - 1) row = M - 1;
                const float* xp = In + (size_t)row * D + c0;
                f32x4 v0 = *reinterpret_cast<const f32x4*>(xp);
                f32x4 v1 = *reinterpret_cast<const f32x4*>(xp + 4);
                #pragma unroll
                for (int e = 0; e < 4; e++) a[e]     = (bf16_t)((v0[e] - stats_s[c0 + e])     * stats_s[16 + c0 + e]);
                #pragma unroll
                for (int e = 0; e < 4; e++) a[4 + e] = (bf16_t)((v1[e] - stats_s[c0 + 4 + e]) * stats_s[16 + c0 + 4 + e]);
            } else {
                #pragma unroll
                for (int e = 0; e < 8; e++) a[e] = (bf16_t)0.f;
            }
            #pragma unroll
            for (int nbi = 0; nbi < 2; nbi++)
                acc[mb][nbi] = __builtin_amdgcn_mfma_f32_16x16x32_bf16(
                    wfr[nbi], a, acc[mb][nbi], 0, 0, 0);
        }

        #pragma unroll
        for (int nbi = 0; nbi < 2; nbi++) {
            const f32x4 bias = *reinterpret_cast<const f32x4*>(
                b1p + j * 256 + wave * 32 + nbi * 16 + quad * 4);
            char* wp = wbase + ((wlow0 ^ (nbi << 1)) << 4);
            #pragma unroll
            for (int mb = 0; mb < 8; mb++) {
                bf16x4 pk;
                #pragma unroll
                for (int r = 0; r < 4; r++) {
                    float v = acc[mb][nbi][r] + bias[r];
                    v = fmaxf(v, 0.01f * v);
                    pk[r] = (bf16_t)v;
                }
                *reinterpret_cast<bf16x4*>(wp + mb * 8192) = pk;
            }
        }
    }
    __syncthreads();

    // ---------------- layer 2 (256x256), depth-3 weight ring ----------------
    {
        f32x4 acc[8][2];
        #pragma unroll
        for (int a = 0; a < 8; a++) { acc[a][0] = vzero; acc[a][1] = vzero; }

        const bf16_t* w2base = W2t + ((size_t)j * 256 + wave * 32 + l16) * 256 + quad * 8;

        bf16x8 wr[3][2];
        #pragma unroll
        for (int d = 0; d < 3; d++)
            #pragma unroll
            for (int nbi = 0; nbi < 2; nbi++)
                wr[d][nbi] = *reinterpret_cast<const bf16x8*>(w2base + nbi * 4096 + d * 32);

        #pragma unroll
        for (int kk = 0; kk < 8; kk++) {
            const int c = kk % 3;
            const char* ap = abase + ((kk ^ hi2) << 6);
            bf16x8 av0[4];
            #pragma unroll
            for (int mb = 0; mb < 4; mb++)
                av0[mb] = *reinterpret_cast<const bf16x8*>(ap + mb * 8192);
            #pragma unroll
            for (int nbi = 0; nbi < 2; nbi++)
                #pragma unroll
                for (int mb = 0; mb < 4; mb++)
                    acc[mb][nbi] = __builtin_amdgcn_mfma_f32_16x16x32_bf16(
                        wr[c][nbi], av0[mb], acc[mb][nbi], 0, 0, 0);
            bf16x8 av1[4];
            #pragma unroll
            for (int mb = 0; mb < 4; mb++)
                av1[mb] = *reinterpret_cast<const bf16x8*>(ap + (mb + 4) * 8192);
            #pragma unroll
            for (int nbi = 0; nbi < 2; nbi++)
                #pragma unroll
                for (int mb = 4; mb < 8; mb++)
                    acc[mb][nbi] = __builtin_amdgcn_mfma_f32_16x16x32_bf16(
                        wr[c][nbi], av1[mb - 4], acc[mb][nbi], 0, 0, 0);
            if (kk < 5) {
                #pragma unroll
                for (int nbi = 0; nbi < 2; nbi++)
                    wr[c][nbi] = *reinterpret_cast<const bf16x8*>(
                        w2base + nbi * 4096 + (kk + 3) * 32);
            }
        }
        __syncthreads();
        #pragma unroll
        for (int nbi = 0; nbi < 2; nbi++) {
            const f32x4 bias = *reinterpret_cast<const f32x4*>(
                b2 + j * 256 + wave * 32 + nbi * 16 + quad * 4);
            char* wp = wbase + ((wlow0 ^ (nbi << 1)) << 4);
            #pragma unroll
            for (int mb = 0; mb < 8; mb++) {
                bf16x4 pk;
                #pragma unroll
                for (int r = 0; r < 4; r++) {
                    float v = acc[mb][nbi][r] + bias[r];
                    v = fmaxf(v, 0.01f * v);
                    pk[r] = (bf16_t)v;
                }
                *reinterpret_cast<bf16x4*>(wp + mb * 8192) = pk;
            }
        }
    }
    __syncthreads();

    // ---------------- layer 3 (256x128), depth-3 weight ring ----------------
    {
        f32x4 acc[8];
        #pragma unroll
        for (int a = 0; a < 8; a++) acc[a] = vzero;

        const bf16_t* w3base = W3t + ((size_t)j * 128 + wave * 16 + l16) * 256 + quad * 8;

        bf16x8 wr[3];
        #pragma unroll
        for (int d = 0; d < 3; d++)
            wr[d] = *reinterpret_cast<const bf16x8*>(w3base + d * 32);

        #pragma unroll
        for (int kk = 0; kk < 8; kk++) {
            const int c = kk % 3;
            const char* ap = abase + ((kk ^ hi2) << 6);
            bf16x8 av0[4];
            #pragma unroll
            for (int mb = 0; mb < 4; mb++)
                av0[mb] = *reinterpret_cast<const bf16x8*>(ap + mb * 8192);
            #pragma unroll
            for (int mb = 0; mb < 4; mb++)
                acc[mb] = __builtin_amdgcn_mfma_f32_16x16x32_bf16(
                    wr[c], av0[mb], acc[mb], 0, 0, 0);
            bf16x8 av1[4];
            #pragma unroll
            for (int mb = 0; mb < 4; mb++)
                av1[mb] = *reinterpret_cast<const bf16x8*>(ap + (mb + 4) * 8192);
            #pragma unroll
            for (int mb = 4; mb < 8; mb++)
                acc[mb] = __builtin_amdgcn_mfma_f32_16x16x32_bf16(
                    wr[c], av1[mb - 4], acc[mb], 0, 0, 0);
            if (kk < 5)
                wr[c] = *reinterpret_cast<const bf16x8*>(w3base + (kk + 3) * 32);
        }
        __syncthreads();   // hs reusable as [128][128]
        {
            const int sp3 = (wave * 2 + (quad >> 1)) ^ l16;
            char* w3p = hsB + l16 * 256 + sp3 * 16 + ((quad & 1) << 3);
            #pragma unroll
            for (int mb = 0; mb < 8; mb++) {
                bf16x4 pk;
                #pragma unroll
                for (int r = 0; r < 4; r++) pk[r] = (bf16_t)acc[mb][r];
                *reinterpret_cast<bf16x4*>(w3p + mb * 4096) = pk;
            }
        }
    }
    __syncthreads();
    #pragma unroll
    for (int p = 0; p < 4; p++) {
        const int rr = p * 32 + (tid >> 4);
        const int s  = tid & 15;
        if (row0 + rr < M) {
            bf16x8 v = *reinterpret_cast<const bf16x8*>(hs + rr * 128 + (s ^ (rr & 15)) * 8);
            *reinterpret_cast<bf16x8*>(outp + (size_t)j * JS + (size_t)(row0 + rr) * 128 + s * 8) = v;
        }
    }
}

// ---------------------------------------------------------------------------
// Koopman scan v3 (verbatim R9 — verified best; R10's in-wave v4 regressed
// 18us from coalescing loss + halved TLP). Grid 1024 = 64 b x 8 jg x 2 th.
// th=0 handles t in [0,32), th=1 handles [32,63) after a barrier-free
// register replay of u_0..u_31. Serial chain 63 -> 32 iterations.
__global__ __launch_bounds__(512) void scan_kernel(
    const bf16_t* __restrict__ phi, const bf16_t* __restrict__ psiu,
    const float* __restrict__ psi0, const float* __restrict__ reL,
    const float* __restrict__ imL, const float* __restrict__ C_W,
    float* __restrict__ y, float* __restrict__ ypred) {
    const int bid = blockIdx.x;
    const int th = bid & 1;              // t-range half
    const int jg = (bid >> 1) & 7;
    const int b  = bid >> 4;
    const int tid = threadIdx.x;
    const int wave = tid >> 6, lane = tid & 63;
    __shared__ float redP[2][8][128];
    __shared__ float redY[2][8][128];
    __shared__ float SPb[8][132];
    __shared__ float SYb[8][132];
    __shared__ float CsT[2048];          // CsT[i*16+o] = C_W[o*128+i]
    #pragma unroll
    for (int i = 0; i < 4; i++) {
        const int idx = tid + i * 512;
        CsT[(idx & 127) * 16 + (idx >> 7)] = C_W[idx];
    }

    const int tb = th * 32;
    const int te = th ? 63 : 32;

    const int j0 = jg * 8 + wave;        // one net per wave
    float sx, sy, p0x, p0y, lre, lim;
    {
        unsigned v = *reinterpret_cast<const unsigned*>(
            phi + (size_t)j0 * PHI_JS + (size_t)(b * 64) * 128 + lane * 2);
        sx = __uint_as_float(v << 16); sy = __uint_as_float(v & 0xFFFF0000u);
        float2 p0 = *reinterpret_cast<const float2*>(psi0 + j0 * 128 + lane * 2);
        p0x = p0.x; p0y = p0.y;
        lre = reL[j0]; lim = imL[j0];
    }
    const bf16_t* up = psiu + (size_t)j0 * PSIU_JS + (size_t)(b * 63) * 128 + lane * 2;
    const bf16_t* pp = phi  + (size_t)j0 * PHI_JS  + (size_t)(b * 64 + 1) * 128 + lane * 2;

    // head loads for the output loop — issued before the presum so the
    // L3 latency hides under the presum compute
    unsigned cu0 = *reinterpret_cast<const unsigned*>(up + tb * 128);
    unsigned cp0 = *reinterpret_cast<const unsigned*>(pp + tb * 128);
    unsigned nu1 = *reinterpret_cast<const unsigned*>(up + (tb + 1) * 128);
    unsigned np1 = *reinterpret_cast<const unsigned*>(pp + (tb + 1) * 128);

    // ---- presum replay for th=1: fold u_0..u_31, no barriers/output ----
    if (th) {
        #pragma unroll
        for (int c = 0; c < 2; c++) {
            unsigned buf[16];
            #pragma unroll
            for (int i = 0; i < 16; i++)
                buf[i] = *reinterpret_cast<const unsigned*>(up + (c * 16 + i) * 128);
            #pragma unroll
            for (int i = 0; i < 16; i++) {
                float px = sx + (__uint_as_float(buf[i] << 16) - p0x);
                float py = sy + (__uint_as_float(buf[i] & 0xFFFF0000u) - p0y);
                sx = px * lre - py * lim;
                sy = px * lim + py * lre;
            }
        }
    }

    const int ds  = (tid >> 7) & 1;      // decode: stream (tid<256 active)
    const int dr  = tid & 127;
    const int dtt = dr >> 4, doo = dr & 15;

    int tbase = tb;
    for (int t = tb; t < te; t++) {
        unsigned nu2 = 0, np2 = 0;
        if (t < 61) {
            nu2 = *reinterpret_cast<const unsigned*>(up + (t + 2) * 128);
            np2 = *reinterpret_cast<const unsigned*>(pp + (t + 2) * 128);
        }
        float px = sx + (__uint_as_float(cu0 << 16) - p0x);
        float py = sy + (__uint_as_float(cu0 & 0xFFFF0000u) - p0y);
        sx = px * lre - py * lim;
        sy = px * lim + py * lre;
        const float yx = __uint_as_float(cp0 << 16);
        const float yy = __uint_as_float(cp0 & 0xFFFF0000u);
        const int db = t & 1;
        redP[db][wave][lane * 2]     = sx;
        redP[db][wave][lane * 2 + 1] = sy;
        redY[db][wave][lane * 2]     = yx;
        redY[db][wave][lane * 2 + 1] = yy;
        __syncthreads();
        const int slot = (t - tb) & 7;
        if (tid < 128) {
            SPb[slot][tid] =
                redP[db][0][tid] + redP[db][1][tid] + redP[db][2][tid] + redP[db][3][tid]
              + redP[db][4][tid] + redP[db][5][tid] + redP[db][6][tid] + redP[db][7][tid];
        } else if (tid < 256) {
            const int tl = tid - 128;
            SYb[slot][tl] =
                redY[db][0][tl] + redY[db][1][tl] + redY[db][2][tl] + redY[db][3][tl]
              + redY[db][4][tl] + redY[db][5][tl] + redY[db][6][tl] + redY[db][7][tl];
        }
        cu0 = nu1; cp0 = np1; nu1 = nu2; np1 = np2;
        if (slot == 7 || t == te - 1) {
            __syncthreads();
            if (tid < 256 && dtt <= slot) {
                const float* S = ds ? SYb[dtt] : SPb[dtt];
                float acc = 0.f;
                #pragma unroll
                for (int i = 0; i < 128; i++) acc += S[i] * CsT[i * 16 + doo];
                float* dst = ds ? (y     + (b * 63 + tbase + dtt) * 16 + doo)
                                : (ypred + (b * 63 + tbase + dtt) * 16 + doo);
                atomicAdd(dst, acc);
            }
            __syncthreads();
            tbase = t + 1;
        }
    }
}

// ---------------------------------------------------------------------------
extern "C" void kernel_launch(void* const* d_in, const int* in_sizes, int n_in,
                              void* d_out, int out_size, void* d_ws, size_t ws_size,
                              hipStream_t stream) {
    const float* xs      = (const float*)d_in[0];
    const float* us      = (const float*)d_in[1];
    const float* x_gamma = (const float*)d_in[2];
    const float* x_beta  = (const float*)d_in[3];
    const float* xW1     = (const float*)d_in[4];
    const float* xb1     = (const float*)d_in[5];
    const float* xW2     = (const float*)d_in[6];
    const float* xb2     = (const float*)d_in[7];
    const float* xW3     = (const float*)d_in[8];
    const float* x_scale = (const float*)d_in[9];
    const float* u_gamma = (const float*)d_in[10];
    const float* u_beta  = (const float*)d_in[11];
    const float* uW1     = (const float*)d_in[12];
    const float* ub1     = (const float*)d_in[13];
    const float* uW2     = (const float*)d_in[14];
    const float* ub2     = (const float*)d_in[15];
    const float* uW3     = (const float*)d_in[16];
    const float* u_scale = (const float*)d_in[17];
    const float* reL     = (const float*)d_in[18];
    const float* imL     = (const float*)d_in[19];
    const float* C_W     = (const float*)d_in[20];

    char* ws = (char*)d_ws;
    size_t off = 0;
    auto alloc = [&](size_t bytes) -> char* {
        char* p = ws + off;
        off += (bytes + 255) & ~(size_t)255;
        return p;
    };
    float*  part = (float*)alloc(96 * 32 * 4);
    bf16_t* xW1t = (bf16_t*)alloc((size_t)64 * 256 * 32 * 2);
    float*  xb1p = (float*) alloc((size_t)64 * 256 * 4);
    bf16_t* xW2t = (bf16_t*)alloc((size_t)64 * 256 * 256 * 2);
    bf16_t* xW3t = (bf16_t*)alloc((size_t)64 * 128 * 256 * 2);
    bf16_t* uW1t = (bf16_t*)alloc((size_t)64 * 256 * 32 * 2);
    float*  ub1p = (float*) alloc((size_t)64 * 256 * 4);
    bf16_t* uW2t = (bf16_t*)alloc((size_t)64 * 256 * 256 * 2);
    bf16_t* uW3t = (bf16_t*)alloc((size_t)64 * 128 * 256 * 2);
    float*  psi0 = (float*) alloc((size_t)64 * 128 * 4);
    bf16_t* phi  = (bf16_t*)alloc((size_t)64 * PHI_JS  * 2);   // [j][4096][128] + pad
    bf16_t* psiu = (bf16_t*)alloc((size_t)64 * PSIU_JS * 2);   // [j][4032][128] + pad

    float* y_out     = (float*)d_out;
    float* ypred_out = y_out + 64 * 63 * 16;

    prep_all_kernel<<<3360, 256, 0, stream>>>(
        xW1, xb1, x_gamma, x_beta, uW1, ub1, u_gamma, u_beta,
        xW2, uW2, xW3, uW3, x_scale, u_scale, xs, us,
        xW1t, xb1p, uW1t, ub1p, xW2t, uW2t, xW3t, uW3t, part, y_out);
    fused_mlp_kernel<<<4160, 512, 0, stream>>>(
        xs, us, part,
        xW1t, xb1p, xW2t, xb2, xW3t, uW1t, ub1p, uW2t, ub2, uW3t,
        uW1, ub1, u_beta, uW2, uW3, u_scale, psi0,
        phi, psiu);
    scan_kernel<<<1024, 512, 0, stream>>>(
        phi, psiu, psi0, reL, imL, C_W, y_out, ypred_out);
}